// Round 1
// baseline (663.963 us; speedup 1.0000x reference)
//
#include <hip/hip_runtime.h>

namespace {

constexpr int HW = 128 * 128;   // 16384 pixels per image
constexpr int C  = 192;
constexpr int C3 = 576;
constexpr int CH = 48;          // head dim

// ---------------- GEMM: Co[M,N] = A[M,192] @ W[192,N]  (fp32, 64x64 tile) ----
template <int N>
__global__ __launch_bounds__(256) void gemm_k192(const float* __restrict__ A,
                                                 const float* __restrict__ Wm,
                                                 float* __restrict__ Co) {
  constexpr int K = 192;
  __shared__ float As[32][68];   // [k][m], pad 68 -> conflict-ok stores, aligned b128 reads
  __shared__ float Bs[32][64];   // [k][n]
  const int tid = threadIdx.x;
  const int m0 = blockIdx.x * 64;
  const int n0 = blockIdx.y * 64;
  const int tx = tid & 15;
  const int ty = tid >> 4;
  float acc[4][4] = {};
  for (int k0 = 0; k0 < K; k0 += 32) {
#pragma unroll
    for (int r = 0; r < 2; ++r) {
      const int idx = tid + r * 256;       // 512 float4 of A tile
      const int row = idx >> 3;            // 0..63 (m)
      const int kf4 = idx & 7;             // 0..7  (k/4)
      const float4 a = *(const float4*)&A[(size_t)(m0 + row) * K + k0 + kf4 * 4];
      As[kf4 * 4 + 0][row] = a.x;
      As[kf4 * 4 + 1][row] = a.y;
      As[kf4 * 4 + 2][row] = a.z;
      As[kf4 * 4 + 3][row] = a.w;
    }
#pragma unroll
    for (int r = 0; r < 2; ++r) {
      const int idx = tid + r * 256;       // 512 float4 of B tile
      const int row = idx >> 4;            // 0..31 (k)
      const int c4 = idx & 15;             // 0..15 (n/4)
      *(float4*)&Bs[row][c4 * 4] = *(const float4*)&Wm[(size_t)(k0 + row) * N + n0 + c4 * 4];
    }
    __syncthreads();
#pragma unroll
    for (int k = 0; k < 32; ++k) {
      const float4 av = *(const float4*)&As[k][ty * 4];
      const float4 bv = *(const float4*)&Bs[k][tx * 4];
      const float a_[4] = {av.x, av.y, av.z, av.w};
      const float b_[4] = {bv.x, bv.y, bv.z, bv.w};
#pragma unroll
      for (int i = 0; i < 4; ++i)
#pragma unroll
        for (int j = 0; j < 4; ++j) acc[i][j] += a_[i] * b_[j];
    }
    __syncthreads();
  }
#pragma unroll
  for (int i = 0; i < 4; ++i) {
    float4 o;
    o.x = acc[i][0]; o.y = acc[i][1]; o.z = acc[i][2]; o.w = acc[i][3];
    *(float4*)&Co[(size_t)(m0 + ty * 4 + i) * N + n0 + tx * 4] = o;
  }
}

// ---------------- depthwise 3x3 SAME over 576 channels (one image) ----------
__global__ __launch_bounds__(256) void dwconv3x3(const float* __restrict__ in,
                                                 const float* __restrict__ wdw,
                                                 float* __restrict__ outp) {
  const int t = blockIdx.x * 256 + threadIdx.x;  // float4 index, 0..HW*144-1
  const int c4 = t % 144;
  const int p = t / 144;
  const int y = p >> 7;
  const int x = p & 127;
  float4 acc = make_float4(0.f, 0.f, 0.f, 0.f);
#pragma unroll
  for (int dy = -1; dy <= 1; ++dy) {
    const int yy = y + dy;
    if ((unsigned)yy >= 128u) continue;
#pragma unroll
    for (int dx = -1; dx <= 1; ++dx) {
      const int xx = x + dx;
      if ((unsigned)xx >= 128u) continue;
      const float4 v = *(const float4*)&in[(size_t)((yy << 7) + xx) * C3 + c4 * 4];
      const float4 w = *(const float4*)&wdw[(size_t)((dy + 1) * 3 + (dx + 1)) * C3 + c4 * 4];
      acc.x += v.x * w.x;
      acc.y += v.y * w.y;
      acc.z += v.z * w.z;
      acc.w += v.w * w.w;
    }
  }
  *(float4*)&outp[(size_t)t * 4] = acc;
}

// ------- Gram: G[h][c][d] += sum_s q[s,c]*k[s,d]; also row sum-of-squares ---
__global__ __launch_bounds__(256) void gram48(const float* __restrict__ dwq,
                                              float* __restrict__ G,
                                              float* __restrict__ ssqq,
                                              float* __restrict__ ssqk) {
  __shared__ float qs[64][48];
  __shared__ float ks[64][48];
  const int tid = threadIdx.x;
  const int h = blockIdx.y;
  const int s0 = blockIdx.x * 256;
  const int qoff = h * CH;
  const int koff = C + h * CH;
  const int c3 = (tid >> 4) * 3;
  const int d3 = (tid & 15) * 3;
  float acc[3][3] = {};
  float sq = 0.f, sk = 0.f;
  for (int sub = 0; sub < 4; ++sub) {
    const int sbase = s0 + sub * 64;
#pragma unroll
    for (int r = 0; r < 3; ++r) {
      const int idx = tid + r * 256;   // 768 float4 per buffer
      const int row = idx / 12;
      const int cc4 = idx % 12;
      const float* src = &dwq[(size_t)(sbase + row) * C3];
      *(float4*)&qs[row][cc4 * 4] = *(const float4*)&src[qoff + cc4 * 4];
      *(float4*)&ks[row][cc4 * 4] = *(const float4*)&src[koff + cc4 * 4];
    }
    __syncthreads();
#pragma unroll 4
    for (int s = 0; s < 64; ++s) {
      const float qv[3] = {qs[s][c3], qs[s][c3 + 1], qs[s][c3 + 2]};
      const float kv[3] = {ks[s][d3], ks[s][d3 + 1], ks[s][d3 + 2]};
#pragma unroll
      for (int i = 0; i < 3; ++i)
#pragma unroll
        for (int j = 0; j < 3; ++j) acc[i][j] += qv[i] * kv[j];
    }
    if (tid < 48) {
#pragma unroll 4
      for (int s = 0; s < 64; ++s) { const float v = qs[s][tid]; sq += v * v; }
    } else if (tid >= 64 && tid < 112) {
      const int cc = tid - 64;
#pragma unroll 4
      for (int s = 0; s < 64; ++s) { const float v = ks[s][cc]; sk += v * v; }
    }
    __syncthreads();
  }
  float* Gm = &G[h * 2304];
#pragma unroll
  for (int i = 0; i < 3; ++i)
#pragma unroll
    for (int j = 0; j < 3; ++j) atomicAdd(&Gm[(c3 + i) * 48 + d3 + j], acc[i][j]);
  if (tid < 48) atomicAdd(&ssqq[h * CH + tid], sq);
  else if (tid >= 64 && tid < 112) atomicAdd(&ssqk[h * CH + tid - 64], sk);
}

// ---- scale by temp / (|q||k|), softmax over d (48), one wave per row -------
__global__ __launch_bounds__(64) void attn_softmax(const float* __restrict__ G,
                                                   const float* __restrict__ ssqq,
                                                   const float* __restrict__ ssqk,
                                                   const float* __restrict__ temp,
                                                   float* __restrict__ attn) {
  const int r = blockIdx.x;   // 0..47
  const int h = blockIdx.y;   // 0..3
  const int lane = threadIdx.x;
  const float t = temp[h];
  const float qn = ssqq[h * CH + r];
  float val = -1e30f;
  if (lane < 48) {
    const float kn = ssqk[h * CH + lane];
    val = G[h * 2304 + r * 48 + lane] * t * rsqrtf(qn * kn);
  }
  float m = val;
#pragma unroll
  for (int off = 32; off; off >>= 1) m = fmaxf(m, __shfl_xor(m, off));
  const float e = (lane < 48) ? expf(val - m) : 0.f;
  float ssum = e;
#pragma unroll
  for (int off = 32; off; off >>= 1) ssum += __shfl_xor(ssum, off);
  if (lane < 48) attn[h * 2304 + r * 48 + lane] = e / ssum;
}

// ---- out2[s, (h,cc)] = sum_d attn[h][cc][d] * v[s][(h,d)] ------------------
__global__ __launch_bounds__(192) void attn_v(const float* __restrict__ dwq,
                                              const float* __restrict__ attnb,
                                              float* __restrict__ out2) {
  __shared__ float vs[64][192];
  const int tid = threadIdx.x;   // 0..191  -> output channel
  const int s0 = blockIdx.x * 64;
#pragma unroll
  for (int r = 0; r < 16; ++r) {
    const int idx = tid + r * 192;     // 3072 float4
    const int row = idx / 48;
    const int cc4 = idx % 48;
    *(float4*)&vs[row][cc4 * 4] =
        *(const float4*)&dwq[(size_t)(s0 + row) * C3 + 2 * C + cc4 * 4];
  }
  const int h = tid / 48;
  const int cc = tid % 48;
  float areg[48];
#pragma unroll
  for (int d4 = 0; d4 < 12; ++d4) {
    const float4 av = *(const float4*)&attnb[h * 2304 + cc * 48 + d4 * 4];
    areg[d4 * 4 + 0] = av.x;
    areg[d4 * 4 + 1] = av.y;
    areg[d4 * 4 + 2] = av.z;
    areg[d4 * 4 + 3] = av.w;
  }
  __syncthreads();
  const int vb = h * 48;
  float* ob = &out2[(size_t)s0 * C + tid];
  for (int s = 0; s < 64; ++s) {
    float a = 0.f;
#pragma unroll
    for (int d = 0; d < 48; ++d) a += areg[d] * vs[s][vb + d];
    ob[(size_t)s * C] = a;
  }
}

}  // namespace

extern "C" void kernel_launch(void* const* d_in, const int* in_sizes, int n_in,
                              void* d_out, int out_size, void* d_ws, size_t ws_size,
                              hipStream_t stream) {
  const float* x      = (const float*)d_in[0];
  const float* w_qkv  = (const float*)d_in[1];
  const float* w_dw   = (const float*)d_in[2];
  const float* w_proj = (const float*)d_in[3];
  const float* temp   = (const float*)d_in[4];
  float* out = (float*)d_out;

  // per-image scratch layout (peak ~76 MB)
  char* ws = (char*)d_ws;
  float* qkvb   = (float*)ws;                         // HW*576*4 = 37,748,736 B
  float* dwqkvb = (float*)(ws + 37748736);            // 37,748,736 B
  float* out2b  = qkvb;                               // reuse (qkv dead after dwconv)
  char* tail = ws + 2 * 37748736;
  float* G     = (float*)tail;                        // 16*2304*4 = 147456 B
  float* ssqq  = (float*)(tail + 147456);             // 768*4
  float* ssqk  = (float*)(tail + 150528);             // 768*4
  float* attnb = (float*)(tail + 153600);             // 147456 B

  // zero Gram + sumsq accumulators (every call: atomics accumulate into them)
  hipMemsetAsync(G, 0, 153600, stream);

  for (int b = 0; b < 4; ++b) {
    const float* xb = x + (size_t)b * HW * C;
    float* Gb  = G + b * 4 * 2304;
    float* sqb = ssqq + b * 192;
    float* skb = ssqk + b * 192;
    float* ab  = attnb + b * 4 * 2304;
    gemm_k192<576><<<dim3(HW / 64, 9), 256, 0, stream>>>(xb, w_qkv, qkvb);
    dwconv3x3<<<HW * 144 / 256, 256, 0, stream>>>(qkvb, w_dw, dwqkvb);
    gram48<<<dim3(64, 4), 256, 0, stream>>>(dwqkvb, Gb, sqb, skb);
    attn_softmax<<<dim3(48, 4), 64, 0, stream>>>(Gb, sqb, skb, temp, ab);
    attn_v<<<256, 192, 0, stream>>>(dwqkvb, ab, out2b);
    gemm_k192<192><<<dim3(HW / 64, 3), 256, 0, stream>>>(out2b, w_proj, out + (size_t)b * HW * C);
  }
}

// Round 2
// 532.431 us; speedup vs baseline: 1.2470x; 1.2470x over previous
//
#include <hip/hip_runtime.h>

namespace {

constexpr int HW = 128 * 128;   // 16384 pixels per image
constexpr int C  = 192;
constexpr int C3 = 576;
constexpr int CH = 48;          // head dim

using bf16x8 = __attribute__((ext_vector_type(8))) short;
using f32x4  = __attribute__((ext_vector_type(4))) float;

__device__ inline unsigned short f2bf(float f) {
  unsigned u = __float_as_uint(f);
  unsigned r = (u + 0x7fff + ((u >> 16) & 1)) >> 16;
  return (unsigned short)r;
}
__device__ inline float bf2f(unsigned short b) {
  return __uint_as_float(((unsigned)b) << 16);
}

// ---- split fp32 -> bf16 hi/lo (4 elems/thread) ------------------------------
__global__ __launch_bounds__(256) void cvt_split(const float* __restrict__ in,
                                                 unsigned short* __restrict__ hi,
                                                 unsigned short* __restrict__ lo) {
  const int t = blockIdx.x * 256 + threadIdx.x;
  const float4 v = ((const float4*)in)[t];
  const float vv[4] = {v.x, v.y, v.z, v.w};
  unsigned short h[4], l[4];
#pragma unroll
  for (int j = 0; j < 4; ++j) {
    h[j] = f2bf(vv[j]);
    l[j] = f2bf(vv[j] - bf2f(h[j]));
  }
  ((ushort4*)hi)[t] = make_ushort4(h[0], h[1], h[2], h[3]);
  ((ushort4*)lo)[t] = make_ushort4(l[0], l[1], l[2], l[3]);
}

// ---- transpose + split weights: wqkv [192,576] -> [576,192], wproj -> [192,192]
__global__ __launch_bounds__(256) void cvt_weights(const float* __restrict__ wqkv,
                                                   const float* __restrict__ wproj,
                                                   unsigned short* __restrict__ wqh,
                                                   unsigned short* __restrict__ wql,
                                                   unsigned short* __restrict__ wph,
                                                   unsigned short* __restrict__ wpl) {
  const int t = blockIdx.x * 256 + threadIdx.x;  // 0 .. 768*192-1
  const int n = t / 192;
  const int k = t % 192;
  float v;
  unsigned short *ph, *pl;
  if (n < C3) {
    v = wqkv[k * C3 + n];
    ph = &wqh[n * 192 + k];
    pl = &wql[n * 192 + k];
  } else {
    const int nn = n - C3;
    v = wproj[k * C + nn];
    ph = &wph[nn * 192 + k];
    pl = &wpl[nn * 192 + k];
  }
  const unsigned short h = f2bf(v);
  *ph = h;
  *pl = f2bf(v - bf2f(h));
}

// ---- MFMA GEMM: Co[M,N] = (Ah+Al)[M,192] @ (Bh+Bl)^T, Bt row-major [N,192] --
// 3-pass split: AhBh + AhBl + AlBh. Tile 128x64, 4 waves (2x2), K-step 32.
// LDS XOR swizzle: 16B slot s at row r stored at slot s^(r&3)  (G4/T2 pattern)
template <int N>
__global__ __launch_bounds__(256, 3) void gemm_mfma(const unsigned short* __restrict__ Ah,
                                                    const unsigned short* __restrict__ Al,
                                                    const unsigned short* __restrict__ Bh,
                                                    const unsigned short* __restrict__ Bl,
                                                    float* __restrict__ Co) {
  constexpr int K = 192;
  __shared__ __align__(16) unsigned short sAh[2][128 * 32];
  __shared__ __align__(16) unsigned short sAl[2][128 * 32];
  __shared__ __align__(16) unsigned short sBh[2][64 * 32];
  __shared__ __align__(16) unsigned short sBl[2][64 * 32];
  const int t = threadIdx.x;
  const int lane = t & 63;
  const int wid = t >> 6;
  const int m0 = blockIdx.x * 128;
  const int n0 = blockIdx.y * 64;
  const int wr = wid >> 1, wc = wid & 1;
  const int fr_row = lane & 15;
  const int fr_swz = ((lane >> 4) ^ (lane & 3)) << 3;

  f32x4 acc[4][2] = {};
  bf16x8 rg[6];

  auto stage_load = [&](int k0) {
#pragma unroll
    for (int r = 0; r < 2; ++r) {
      const int idx = t + (r << 8);
      const int row = idx >> 2, sl = idx & 3;
      const size_t go = (size_t)(m0 + row) * K + k0 + (sl << 3);
      rg[r]     = *(const bf16x8*)&Ah[go];
      rg[2 + r] = *(const bf16x8*)&Al[go];
    }
    {
      const int row = t >> 2, sl = t & 3;
      const size_t go = (size_t)(n0 + row) * K + k0 + (sl << 3);
      rg[4] = *(const bf16x8*)&Bh[go];
      rg[5] = *(const bf16x8*)&Bl[go];
    }
  };
  auto stage_write = [&](int buf) {
#pragma unroll
    for (int r = 0; r < 2; ++r) {
      const int idx = t + (r << 8);
      const int row = idx >> 2, sl = idx & 3;
      const int ph = row * 32 + ((sl ^ (row & 3)) << 3);
      *(bf16x8*)&sAh[buf][ph] = rg[r];
      *(bf16x8*)&sAl[buf][ph] = rg[2 + r];
    }
    {
      const int row = t >> 2, sl = t & 3;
      const int ph = row * 32 + ((sl ^ (row & 3)) << 3);
      *(bf16x8*)&sBh[buf][ph] = rg[4];
      *(bf16x8*)&sBl[buf][ph] = rg[5];
    }
  };

  stage_load(0);
  stage_write(0);
  __syncthreads();
#pragma unroll
  for (int ks = 0; ks < 6; ++ks) {
    if (ks < 5) stage_load((ks + 1) * 32);
    // compute on buf ks&1
    {
      const int buf = ks & 1;
      bf16x8 fah[4], fal[4], fbh[2], fbl[2];
#pragma unroll
      for (int i = 0; i < 4; ++i) {
        const int row = wr * 64 + i * 16 + fr_row;
        fah[i] = *(const bf16x8*)&sAh[buf][row * 32 + fr_swz];
        fal[i] = *(const bf16x8*)&sAl[buf][row * 32 + fr_swz];
      }
#pragma unroll
      for (int j = 0; j < 2; ++j) {
        const int row = wc * 32 + j * 16 + fr_row;
        fbh[j] = *(const bf16x8*)&sBh[buf][row * 32 + fr_swz];
        fbl[j] = *(const bf16x8*)&sBl[buf][row * 32 + fr_swz];
      }
#pragma unroll
      for (int i = 0; i < 4; ++i)
#pragma unroll
        for (int j = 0; j < 2; ++j) {
          acc[i][j] = __builtin_amdgcn_mfma_f32_16x16x32_bf16(fah[i], fbh[j], acc[i][j], 0, 0, 0);
          acc[i][j] = __builtin_amdgcn_mfma_f32_16x16x32_bf16(fah[i], fbl[j], acc[i][j], 0, 0, 0);
          acc[i][j] = __builtin_amdgcn_mfma_f32_16x16x32_bf16(fal[i], fbh[j], acc[i][j], 0, 0, 0);
        }
    }
    if (ks < 5) {
      __syncthreads();
      stage_write((ks + 1) & 1);
      __syncthreads();
    }
  }

  const int er = (lane >> 4) << 2;  // C/D: col=lane&15, row=(lane>>4)*4+reg
  const int ec = lane & 15;
#pragma unroll
  for (int i = 0; i < 4; ++i)
#pragma unroll
    for (int j = 0; j < 2; ++j) {
      float* cp = &Co[(size_t)(m0 + wr * 64 + i * 16 + er) * N + n0 + wc * 32 + j * 16 + ec];
#pragma unroll
      for (int r = 0; r < 4; ++r) cp[(size_t)r * N] = acc[i][j][r];
    }
}

// ---------------- depthwise 3x3 SAME over 576 channels (one image) ----------
__global__ __launch_bounds__(256) void dwconv3x3(const float* __restrict__ in,
                                                 const float* __restrict__ wdw,
                                                 float* __restrict__ outp) {
  const int t = blockIdx.x * 256 + threadIdx.x;  // float4 index, 0..HW*144-1
  const int c4 = t % 144;
  const int p = t / 144;
  const int y = p >> 7;
  const int x = p & 127;
  float4 acc = make_float4(0.f, 0.f, 0.f, 0.f);
#pragma unroll
  for (int dy = -1; dy <= 1; ++dy) {
    const int yy = y + dy;
    if ((unsigned)yy >= 128u) continue;
#pragma unroll
    for (int dx = -1; dx <= 1; ++dx) {
      const int xx = x + dx;
      if ((unsigned)xx >= 128u) continue;
      const float4 v = *(const float4*)&in[(size_t)((yy << 7) + xx) * C3 + c4 * 4];
      const float4 w = *(const float4*)&wdw[(size_t)((dy + 1) * 3 + (dx + 1)) * C3 + c4 * 4];
      acc.x += v.x * w.x;
      acc.y += v.y * w.y;
      acc.z += v.z * w.z;
      acc.w += v.w * w.w;
    }
  }
  *(float4*)&outp[(size_t)t * 4] = acc;
}

// ------- Gram: G[h][c][d] += sum_s q[s,c]*k[s,d]; also row sum-of-squares ---
__global__ __launch_bounds__(256) void gram48(const float* __restrict__ dwq,
                                              float* __restrict__ G,
                                              float* __restrict__ ssqq,
                                              float* __restrict__ ssqk) {
  __shared__ float qs[64][48];
  __shared__ float ks[64][48];
  const int tid = threadIdx.x;
  const int h = blockIdx.y;
  const int s0 = blockIdx.x * 256;
  const int qoff = h * CH;
  const int koff = C + h * CH;
  const int c3 = (tid >> 4) * 3;
  const int d3 = (tid & 15) * 3;
  float acc[3][3] = {};
  float sq = 0.f, sk = 0.f;
  for (int sub = 0; sub < 4; ++sub) {
    const int sbase = s0 + sub * 64;
#pragma unroll
    for (int r = 0; r < 3; ++r) {
      const int idx = tid + r * 256;   // 768 float4 per buffer
      const int row = idx / 12;
      const int cc4 = idx % 12;
      const float* src = &dwq[(size_t)(sbase + row) * C3];
      *(float4*)&qs[row][cc4 * 4] = *(const float4*)&src[qoff + cc4 * 4];
      *(float4*)&ks[row][cc4 * 4] = *(const float4*)&src[koff + cc4 * 4];
    }
    __syncthreads();
#pragma unroll 4
    for (int s = 0; s < 64; ++s) {
      const float qv[3] = {qs[s][c3], qs[s][c3 + 1], qs[s][c3 + 2]};
      const float kv[3] = {ks[s][d3], ks[s][d3 + 1], ks[s][d3 + 2]};
#pragma unroll
      for (int i = 0; i < 3; ++i)
#pragma unroll
        for (int j = 0; j < 3; ++j) acc[i][j] += qv[i] * kv[j];
    }
    if (tid < 48) {
#pragma unroll 4
      for (int s = 0; s < 64; ++s) { const float v = qs[s][tid]; sq += v * v; }
    } else if (tid >= 64 && tid < 112) {
      const int cc = tid - 64;
#pragma unroll 4
      for (int s = 0; s < 64; ++s) { const float v = ks[s][cc]; sk += v * v; }
    }
    __syncthreads();
  }
  float* Gm = &G[h * 2304];
#pragma unroll
  for (int i = 0; i < 3; ++i)
#pragma unroll
    for (int j = 0; j < 3; ++j) atomicAdd(&Gm[(c3 + i) * 48 + d3 + j], acc[i][j]);
  if (tid < 48) atomicAdd(&ssqq[h * CH + tid], sq);
  else if (tid >= 64 && tid < 112) atomicAdd(&ssqk[h * CH + tid - 64], sk);
}

// ---- scale by temp / (|q||k|), softmax over d (48), one wave per row -------
__global__ __launch_bounds__(64) void attn_softmax(const float* __restrict__ G,
                                                   const float* __restrict__ ssqq,
                                                   const float* __restrict__ ssqk,
                                                   const float* __restrict__ temp,
                                                   float* __restrict__ attn) {
  const int r = blockIdx.x;   // 0..47
  const int h = blockIdx.y;   // 0..3
  const int lane = threadIdx.x;
  const float t = temp[h];
  const float qn = ssqq[h * CH + r];
  float val = -1e30f;
  if (lane < 48) {
    const float kn = ssqk[h * CH + lane];
    val = G[h * 2304 + r * 48 + lane] * t * rsqrtf(qn * kn);
  }
  float m = val;
#pragma unroll
  for (int off = 32; off; off >>= 1) m = fmaxf(m, __shfl_xor(m, off));
  const float e = (lane < 48) ? expf(val - m) : 0.f;
  float ssum = e;
#pragma unroll
  for (int off = 32; off; off >>= 1) ssum += __shfl_xor(ssum, off);
  if (lane < 48) attn[h * 2304 + r * 48 + lane] = e / ssum;
}

// ---- out2[s, (h,cc)] = sum_d attn[h][cc][d] * v[s][(h,d)] -> bf16 hi/lo ----
__global__ __launch_bounds__(192) void attn_v(const float* __restrict__ dwq,
                                              const float* __restrict__ attnb,
                                              unsigned short* __restrict__ o2h,
                                              unsigned short* __restrict__ o2l) {
  __shared__ float vs[64][192];
  const int tid = threadIdx.x;   // 0..191  -> output channel
  const int s0 = blockIdx.x * 64;
#pragma unroll
  for (int r = 0; r < 16; ++r) {
    const int idx = tid + r * 192;     // 3072 float4
    const int row = idx / 48;
    const int cc4 = idx % 48;
    *(float4*)&vs[row][cc4 * 4] =
        *(const float4*)&dwq[(size_t)(s0 + row) * C3 + 2 * C + cc4 * 4];
  }
  const int h = tid / 48;
  const int cc = tid % 48;
  float areg[48];
#pragma unroll
  for (int d4 = 0; d4 < 12; ++d4) {
    const float4 av = *(const float4*)&attnb[h * 2304 + cc * 48 + d4 * 4];
    areg[d4 * 4 + 0] = av.x;
    areg[d4 * 4 + 1] = av.y;
    areg[d4 * 4 + 2] = av.z;
    areg[d4 * 4 + 3] = av.w;
  }
  __syncthreads();
  const int vb = h * 48;
  unsigned short* oh = &o2h[(size_t)s0 * C + tid];
  unsigned short* ol = &o2l[(size_t)s0 * C + tid];
  for (int s = 0; s < 64; ++s) {
    float a = 0.f;
#pragma unroll
    for (int d = 0; d < 48; ++d) a += areg[d] * vs[s][vb + d];
    const unsigned short hbits = f2bf(a);
    oh[(size_t)s * C] = hbits;
    ol[(size_t)s * C] = f2bf(a - bf2f(hbits));
  }
}

}  // namespace

extern "C" void kernel_launch(void* const* d_in, const int* in_sizes, int n_in,
                              void* d_out, int out_size, void* d_ws, size_t ws_size,
                              hipStream_t stream) {
  const float* x      = (const float*)d_in[0];
  const float* w_qkv  = (const float*)d_in[1];
  const float* w_dw   = (const float*)d_in[2];
  const float* w_proj = (const float*)d_in[3];
  const float* temp   = (const float*)d_in[4];
  float* out = (float*)d_out;

  // workspace layout (~85 MB)
  char* ws = (char*)d_ws;
  float* qkvb   = (float*)ws;                          // 37,748,736 B
  float* dwqkvb = (float*)(ws + 37748736);             // 37,748,736 B
  unsigned short* xh = (unsigned short*)(ws + 75497472);  // 6,291,456 B (reused as o2h)
  unsigned short* xl = (unsigned short*)(ws + 81788928);  // 6,291,456 B (reused as o2l)
  unsigned short* wqh = (unsigned short*)(ws + 88080384); // 221,184 B
  unsigned short* wql = (unsigned short*)(ws + 88301568);
  unsigned short* wph = (unsigned short*)(ws + 88522752); // 73,728 B
  unsigned short* wpl = (unsigned short*)(ws + 88596480);
  float* G     = (float*)(ws + 88670208);              // 147,456 B
  float* ssqq  = (float*)(ws + 88817664);              // 3,072 B
  float* ssqk  = (float*)(ws + 88820736);              // 3,072 B
  float* attnb = (float*)(ws + 88823808);              // 147,456 B

  cvt_weights<<<576, 256, 0, stream>>>(w_qkv, w_proj, wqh, wql, wph, wpl);
  hipMemsetAsync(G, 0, 153600, stream);  // G + ssqq + ssqk (atomic accumulators)

  for (int b = 0; b < 4; ++b) {
    const float* xb = x + (size_t)b * HW * C;
    float* Gb  = G + b * 4 * 2304;
    float* sqb = ssqq + b * 192;
    float* skb = ssqk + b * 192;
    float* ab  = attnb + b * 4 * 2304;
    cvt_split<<<3072, 256, 0, stream>>>(xb, xh, xl);
    gemm_mfma<576><<<dim3(128, 9), 256, 0, stream>>>(xh, xl, wqh, wql, qkvb);
    dwconv3x3<<<HW * 144 / 256, 256, 0, stream>>>(qkvb, w_dw, dwqkvb);
    gram48<<<dim3(64, 4), 256, 0, stream>>>(dwqkvb, Gb, sqb, skb);
    attn_softmax<<<dim3(48, 4), 64, 0, stream>>>(Gb, sqb, skb, temp, ab);
    attn_v<<<256, 192, 0, stream>>>(dwqkvb, ab, xh, xl);  // o2 hi/lo alias x hi/lo
    gemm_mfma<192><<<dim3(128, 3), 256, 0, stream>>>(xh, xl, wph, wpl, out + (size_t)b * HW * C);
  }
}

// Round 3
// 375.801 us; speedup vs baseline: 1.7668x; 1.4168x over previous
//
#include <hip/hip_runtime.h>

namespace {

constexpr int HW = 16384;   // pixels per image
constexpr int C  = 192;
constexpr int C3 = 576;
constexpr int CH = 48;
constexpr int K  = 192;

using bf16x8 = __attribute__((ext_vector_type(8))) short;
using f32x4  = __attribute__((ext_vector_type(4))) float;

__device__ inline unsigned short f2bf(float f) {
  unsigned u = __float_as_uint(f);
  unsigned r = (u + 0x7fff + ((u >> 16) & 1)) >> 16;
  return (unsigned short)r;
}
__device__ inline float bf2f(unsigned short b) {
  return __uint_as_float(((unsigned)b) << 16);
}
__device__ inline void cvt8(float4 a, float4 b, bf16x8& h8, bf16x8& l8) {
  const float v[8] = {a.x, a.y, a.z, a.w, b.x, b.y, b.z, b.w};
#pragma unroll
  for (int j = 0; j < 8; ++j) {
    const unsigned short h = f2bf(v[j]);
    h8[j] = (short)h;
    l8[j] = (short)f2bf(v[j] - bf2f(h));
  }
}

// ---- transpose + split qkv weights: [192,576] -> hi/lo [576][192] ----------
__global__ __launch_bounds__(256) void cvt_wqkv(const float* __restrict__ wqkv,
                                                unsigned short* __restrict__ wqh,
                                                unsigned short* __restrict__ wql) {
  const int t = blockIdx.x * 256 + threadIdx.x;  // 0 .. 576*192-1
  const int n = t / 192;
  const int k = t % 192;
  const float v = wqkv[k * C3 + n];
  const unsigned short h = f2bf(v);
  wqh[n * 192 + k] = h;
  wql[n * 192 + k] = f2bf(v - bf2f(h));
}

// ---- MFMA GEMM: Co[M,N] = A[M,192] @ Bt[N,192]^T, 3-pass bf16 split --------
// CVTA: A is fp32, converted to hi/lo during staging. PERB: B indexed per image.
template <int N, bool CVTA, bool PERB>
__global__ __launch_bounds__(256, 3) void gemm_mfma(const float* __restrict__ Af,
                                                    const unsigned short* __restrict__ Ah,
                                                    const unsigned short* __restrict__ Al,
                                                    const unsigned short* __restrict__ Bh,
                                                    const unsigned short* __restrict__ Bl,
                                                    float* __restrict__ Co) {
  __shared__ __align__(16) unsigned short sAh[2][128 * 32];
  __shared__ __align__(16) unsigned short sAl[2][128 * 32];
  __shared__ __align__(16) unsigned short sBh[2][64 * 32];
  __shared__ __align__(16) unsigned short sBl[2][64 * 32];
  const int t = threadIdx.x;
  const int lane = t & 63;
  const int wid = t >> 6;
  const int m0 = blockIdx.x * 128;
  const int n0 = blockIdx.y * 64;
  const size_t boff = PERB ? (size_t)(m0 >> 14) * (192 * 192) : 0;
  const int wr = wid >> 1, wc = wid & 1;
  const int fr_row = lane & 15;
  const int fr_swz = ((lane >> 4) ^ (lane & 3)) << 3;

  f32x4 acc[4][2] = {};
  bf16x8 rg[6];

  auto stage_load = [&](int k0) {
#pragma unroll
    for (int r = 0; r < 2; ++r) {
      const int idx = t + (r << 8);
      const int row = idx >> 2, sl = idx & 3;
      if constexpr (CVTA) {
        const float* src = &Af[(size_t)(m0 + row) * K + k0 + (sl << 3)];
        const float4 f0 = *(const float4*)src;
        const float4 f1 = *(const float4*)(src + 4);
        cvt8(f0, f1, rg[r], rg[2 + r]);
      } else {
        const size_t go = (size_t)(m0 + row) * K + k0 + (sl << 3);
        rg[r]     = *(const bf16x8*)&Ah[go];
        rg[2 + r] = *(const bf16x8*)&Al[go];
      }
    }
    {
      const int row = t >> 2, sl = t & 3;
      const size_t go = boff + (size_t)(n0 + row) * K + k0 + (sl << 3);
      rg[4] = *(const bf16x8*)&Bh[go];
      rg[5] = *(const bf16x8*)&Bl[go];
    }
  };
  auto stage_write = [&](int buf) {
#pragma unroll
    for (int r = 0; r < 2; ++r) {
      const int idx = t + (r << 8);
      const int row = idx >> 2, sl = idx & 3;
      const int ph = row * 32 + ((sl ^ (row & 3)) << 3);
      *(bf16x8*)&sAh[buf][ph] = rg[r];
      *(bf16x8*)&sAl[buf][ph] = rg[2 + r];
    }
    {
      const int row = t >> 2, sl = t & 3;
      const int ph = row * 32 + ((sl ^ (row & 3)) << 3);
      *(bf16x8*)&sBh[buf][ph] = rg[4];
      *(bf16x8*)&sBl[buf][ph] = rg[5];
    }
  };

  stage_load(0);
  stage_write(0);
  __syncthreads();
#pragma unroll
  for (int ks = 0; ks < 6; ++ks) {
    if (ks < 5) stage_load((ks + 1) * 32);
    {
      const int buf = ks & 1;
      bf16x8 fah[4], fal[4], fbh[2], fbl[2];
#pragma unroll
      for (int i = 0; i < 4; ++i) {
        const int row = wr * 64 + i * 16 + fr_row;
        fah[i] = *(const bf16x8*)&sAh[buf][row * 32 + fr_swz];
        fal[i] = *(const bf16x8*)&sAl[buf][row * 32 + fr_swz];
      }
#pragma unroll
      for (int j = 0; j < 2; ++j) {
        const int row = wc * 32 + j * 16 + fr_row;
        fbh[j] = *(const bf16x8*)&sBh[buf][row * 32 + fr_swz];
        fbl[j] = *(const bf16x8*)&sBl[buf][row * 32 + fr_swz];
      }
#pragma unroll
      for (int i = 0; i < 4; ++i)
#pragma unroll
        for (int j = 0; j < 2; ++j) {
          acc[i][j] = __builtin_amdgcn_mfma_f32_16x16x32_bf16(fah[i], fbh[j], acc[i][j], 0, 0, 0);
          acc[i][j] = __builtin_amdgcn_mfma_f32_16x16x32_bf16(fah[i], fbl[j], acc[i][j], 0, 0, 0);
          acc[i][j] = __builtin_amdgcn_mfma_f32_16x16x32_bf16(fal[i], fbh[j], acc[i][j], 0, 0, 0);
        }
    }
    if (ks < 5) {
      __syncthreads();
      stage_write((ks + 1) & 1);
      __syncthreads();
    }
  }

  const int er = (lane >> 4) << 2;  // C/D: col=lane&15, row=(lane>>4)*4+reg
  const int ec = lane & 15;
#pragma unroll
  for (int i = 0; i < 4; ++i)
#pragma unroll
    for (int j = 0; j < 2; ++j) {
      float* cp = &Co[(size_t)(m0 + wr * 64 + i * 16 + er) * N + n0 + wc * 32 + j * 16 + ec];
#pragma unroll
      for (int r = 0; r < 4; ++r) cp[(size_t)r * N] = acc[i][j][r];
    }
}

// ---- depthwise 3x3 SAME; q,k -> fp32 [p][384], v -> bf16 hi/lo [p][192] ----
__global__ __launch_bounds__(256) void dwconv3x3(const float* __restrict__ in,
                                                 const float* __restrict__ wdw,
                                                 float* __restrict__ dwq,
                                                 unsigned short* __restrict__ vh,
                                                 unsigned short* __restrict__ vl) {
  const int t = blockIdx.x * 256 + threadIdx.x;  // float4 index over npix*144
  const int c4 = t % 144;
  const int p = t / 144;
  const int pi = p & 16383;
  const int imgbase = p - pi;
  const int y = pi >> 7;
  const int x = pi & 127;
  float4 acc = make_float4(0.f, 0.f, 0.f, 0.f);
#pragma unroll
  for (int dy = -1; dy <= 1; ++dy) {
    const int yy = y + dy;
    if ((unsigned)yy >= 128u) continue;
#pragma unroll
    for (int dx = -1; dx <= 1; ++dx) {
      const int xx = x + dx;
      if ((unsigned)xx >= 128u) continue;
      const float4 v = *(const float4*)&in[(size_t)(imgbase + (yy << 7) + xx) * C3 + c4 * 4];
      const float4 w = *(const float4*)&wdw[(size_t)((dy + 1) * 3 + (dx + 1)) * C3 + c4 * 4];
      acc.x += v.x * w.x;
      acc.y += v.y * w.y;
      acc.z += v.z * w.z;
      acc.w += v.w * w.w;
    }
  }
  if (c4 < 96) {
    *(float4*)&dwq[(size_t)p * 384 + c4 * 4] = acc;
  } else {
    const int cc = (c4 - 96) * 4;
    const float vv[4] = {acc.x, acc.y, acc.z, acc.w};
    ushort4 h4, l4;
    unsigned short* hp = (unsigned short*)&h4;
    unsigned short* lp = (unsigned short*)&l4;
#pragma unroll
    for (int j = 0; j < 4; ++j) {
      const unsigned short h = f2bf(vv[j]);
      hp[j] = h;
      lp[j] = f2bf(vv[j] - bf2f(h));
    }
    *(ushort4*)&vh[(size_t)p * 192 + cc] = h4;
    *(ushort4*)&vl[(size_t)p * 192 + cc] = l4;
  }
}

// ------- Gram: G[img][h][c][d] += sum_s q[s,c]*k[s,d]; + row sum-of-squares -
__global__ __launch_bounds__(256) void gram48(const float* __restrict__ dwq,
                                              float* __restrict__ G,
                                              float* __restrict__ ssqq,
                                              float* __restrict__ ssqk) {
  __shared__ float qs[64][48];
  __shared__ float ks[64][48];
  const int tid = threadIdx.x;
  const int h = blockIdx.y;
  const int img = blockIdx.z;
  const int s0 = (img << 14) + blockIdx.x * 256;
  const int qoff = h * CH;
  const int koff = 192 + h * CH;
  const int c3 = (tid >> 4) * 3;
  const int d3 = (tid & 15) * 3;
  float acc[3][3] = {};
  float sq = 0.f, sk = 0.f;
  for (int sub = 0; sub < 4; ++sub) {
    const int sbase = s0 + sub * 64;
#pragma unroll
    for (int r = 0; r < 3; ++r) {
      const int idx = tid + r * 256;
      const int row = idx / 12;
      const int cc4 = idx % 12;
      const float* src = &dwq[(size_t)(sbase + row) * 384];
      *(float4*)&qs[row][cc4 * 4] = *(const float4*)&src[qoff + cc4 * 4];
      *(float4*)&ks[row][cc4 * 4] = *(const float4*)&src[koff + cc4 * 4];
    }
    __syncthreads();
#pragma unroll 4
    for (int s = 0; s < 64; ++s) {
      const float qv[3] = {qs[s][c3], qs[s][c3 + 1], qs[s][c3 + 2]};
      const float kv[3] = {ks[s][d3], ks[s][d3 + 1], ks[s][d3 + 2]};
#pragma unroll
      for (int i = 0; i < 3; ++i)
#pragma unroll
        for (int j = 0; j < 3; ++j) acc[i][j] += qv[i] * kv[j];
    }
    if (tid < 48) {
#pragma unroll 4
      for (int s = 0; s < 64; ++s) { const float v = qs[s][tid]; sq += v * v; }
    } else if (tid >= 64 && tid < 112) {
      const int cc = tid - 64;
#pragma unroll 4
      for (int s = 0; s < 64; ++s) { const float v = ks[s][cc]; sk += v * v; }
    }
    __syncthreads();
  }
  float* Gm = &G[(size_t)(img * 4 + h) * 2304];
#pragma unroll
  for (int i = 0; i < 3; ++i)
#pragma unroll
    for (int j = 0; j < 3; ++j) atomicAdd(&Gm[(c3 + i) * 48 + d3 + j], acc[i][j]);
  if (tid < 48) atomicAdd(&ssqq[img * 192 + h * CH + tid], sq);
  else if (tid >= 64 && tid < 112) atomicAdd(&ssqk[img * 192 + h * CH + tid - 64], sk);
}

// ---- softmax over d of G*temp/(|q||k|), one wave per (img,h,row) -----------
__global__ __launch_bounds__(64) void attn_softmax(const float* __restrict__ G,
                                                   const float* __restrict__ ssqq,
                                                   const float* __restrict__ ssqk,
                                                   const float* __restrict__ temp,
                                                   float* __restrict__ attn) {
  const int r = blockIdx.x;          // 0..47
  const int h = blockIdx.y & 3;
  const int img = blockIdx.y >> 2;
  const int lane = threadIdx.x;
  const size_t base = (size_t)(img * 4 + h) * 2304;
  const float t = temp[h];
  const float qn = ssqq[img * 192 + h * CH + r];
  float val = -1e30f;
  if (lane < 48) {
    const float kn = ssqk[img * 192 + h * CH + lane];
    val = G[base + r * 48 + lane] * t * rsqrtf(qn * kn);
  }
  float m = val;
#pragma unroll
  for (int off = 32; off; off >>= 1) m = fmaxf(m, __shfl_xor(m, off));
  const float e = (lane < 48) ? expf(val - m) : 0.f;
  float ssum = e;
#pragma unroll
  for (int off = 32; off; off >>= 1) ssum += __shfl_xor(ssum, off);
  if (lane < 48) attn[base + r * 48 + lane] = e / ssum;
}

// ---- W_eff^T[img][n][D] = sum_c' A[img][h(D)][c'][D%48] * Wp[48h+c'][n] ----
__global__ __launch_bounds__(256) void make_weff(const float* __restrict__ attn,
                                                 const float* __restrict__ wproj,
                                                 unsigned short* __restrict__ weh,
                                                 unsigned short* __restrict__ wel) {
  const int t = blockIdx.x * 256 + threadIdx.x;   // over NI*192*192
  const int img = t / 36864;
  const int r = t % 36864;
  const int n = r / 192;
  const int D = r % 192;
  const int h = D / 48, dd = D % 48;
  const float* A = &attn[(size_t)(img * 4 + h) * 2304 + dd];
  const float* W = &wproj[(size_t)(h * 48) * 192 + n];
  float acc = 0.f;
#pragma unroll
  for (int c = 0; c < 48; ++c) acc += A[c * 48] * W[c * 192];
  const unsigned short hb = f2bf(acc);
  weh[(size_t)img * 36864 + n * 192 + D] = hb;
  wel[(size_t)img * 36864 + n * 192 + D] = f2bf(acc - bf2f(hb));
}

}  // namespace

extern "C" void kernel_launch(void* const* d_in, const int* in_sizes, int n_in,
                              void* d_out, int out_size, void* d_ws, size_t ws_size,
                              hipStream_t stream) {
  const float* x      = (const float*)d_in[0];
  const float* w_qkv  = (const float*)d_in[1];
  const float* w_dw   = (const float*)d_in[2];
  const float* w_proj = (const float*)d_in[3];
  const float* temp   = (const float*)d_in[4];
  float* out = (float*)d_out;

  // Layout (NI images per pass). Batched NI=4 needs ~303.4 MB; fallback NI=1 ~77 MB.
  auto layout_bytes = [](int NI) -> size_t {
    return (size_t)NI * HW * 576 * 4      // qkv fp32
         + (size_t)NI * HW * 384 * 4      // dwq fp32 (q,k)
         + (size_t)NI * HW * 192 * 2 * 2  // vh, vl
         + 2 * 221184                     // wqh, wql
         + (size_t)NI * (36864 + 768 + 768)  // G, ssqq, ssqk
         + (size_t)NI * 36864 * 4         // attnb
         + (size_t)NI * 36864 * 2 * 2;    // weh, wel
  };
  const int NI = (ws_size >= layout_bytes(4)) ? 4 : 1;
  const int npass = 4 / NI;
  const int npix = NI * HW;

  char* p = (char*)d_ws;
  float* qkv = (float*)p;            p += (size_t)npix * 576 * 4;
  float* dwq = (float*)p;            p += (size_t)npix * 384 * 4;
  unsigned short* vh = (unsigned short*)p;  p += (size_t)npix * 192 * 2;
  unsigned short* vl = (unsigned short*)p;  p += (size_t)npix * 192 * 2;
  unsigned short* wqh = (unsigned short*)p; p += 221184;
  unsigned short* wql = (unsigned short*)p; p += 221184;
  float* G    = (float*)p;           p += (size_t)NI * 36864;
  float* ssqq = (float*)p;           p += (size_t)NI * 768;
  float* ssqk = (float*)p;           p += (size_t)NI * 768;
  float* attnb = (float*)p;          p += (size_t)NI * 36864 * 4;
  unsigned short* weh = (unsigned short*)p; p += (size_t)NI * 36864 * 2;
  unsigned short* wel = (unsigned short*)p;

  cvt_wqkv<<<432, 256, 0, stream>>>(w_qkv, wqh, wql);

  for (int pass = 0; pass < npass; ++pass) {
    const float* xb = x + (size_t)pass * HW * C;
    float* outb = out + (size_t)pass * HW * C;
    // zero atomic accumulators (G + ssqq + ssqk are contiguous)
    hipMemsetAsync(G, 0, (size_t)NI * (36864 + 768 + 768), stream);
    gemm_mfma<576, true, false><<<dim3(npix / 128, 9), 256, 0, stream>>>(
        xb, nullptr, nullptr, wqh, wql, qkv);
    dwconv3x3<<<npix * 144 / 256, 256, 0, stream>>>(qkv, w_dw, dwq, vh, vl);
    gram48<<<dim3(64, 4, NI), 256, 0, stream>>>(dwq, G, ssqq, ssqk);
    attn_softmax<<<dim3(48, 4 * NI), 64, 0, stream>>>(G, ssqq, ssqk, temp, attnb);
    make_weff<<<NI * 144, 256, 0, stream>>>(attnb, w_proj, weh, wel);
    gemm_mfma<192, false, true><<<dim3(npix / 128, 3), 256, 0, stream>>>(
        nullptr, vh, vl, weh, wel, outb);
  }
}

// Round 4
// 325.271 us; speedup vs baseline: 2.0413x; 1.1553x over previous
//
#include <hip/hip_runtime.h>

namespace {

constexpr int HW = 16384;   // pixels per image
constexpr int C  = 192;
constexpr int C3 = 576;
constexpr int CH = 48;
constexpr int K  = 192;

using bf16x8 = __attribute__((ext_vector_type(8))) short;
using f32x4  = __attribute__((ext_vector_type(4))) float;

__device__ inline unsigned short f2bf(float f) {
  unsigned u = __float_as_uint(f);
  unsigned r = (u + 0x7fff + ((u >> 16) & 1)) >> 16;
  return (unsigned short)r;
}
__device__ inline float bf2f(unsigned short b) {
  return __uint_as_float(((unsigned)b) << 16);
}

// ---- split fp32 -> bf16 hi/lo (4 elems/thread), all images -----------------
__global__ __launch_bounds__(256) void cvt_split(const float* __restrict__ in,
                                                 unsigned short* __restrict__ hi,
                                                 unsigned short* __restrict__ lo) {
  const int t = blockIdx.x * 256 + threadIdx.x;
  const float4 v = ((const float4*)in)[t];
  const float vv[4] = {v.x, v.y, v.z, v.w};
  unsigned short h[4], l[4];
#pragma unroll
  for (int j = 0; j < 4; ++j) {
    h[j] = f2bf(vv[j]);
    l[j] = f2bf(vv[j] - bf2f(h[j]));
  }
  ((ushort4*)hi)[t] = make_ushort4(h[0], h[1], h[2], h[3]);
  ((ushort4*)lo)[t] = make_ushort4(l[0], l[1], l[2], l[3]);
}

// ---- transpose + split qkv weights: [192,576] -> hi/lo [576][192] ----------
__global__ __launch_bounds__(256) void cvt_wqkv(const float* __restrict__ wqkv,
                                                unsigned short* __restrict__ wqh,
                                                unsigned short* __restrict__ wql) {
  const int t = blockIdx.x * 256 + threadIdx.x;  // 0 .. 576*192-1
  const int n = t / 192;
  const int k = t % 192;
  const float v = wqkv[k * C3 + n];
  const unsigned short h = f2bf(v);
  wqh[n * 192 + k] = h;
  wql[n * 192 + k] = f2bf(v - bf2f(h));
}

// ---- MFMA GEMM: Co[M,N] = A[M,192] @ Bt[N,192]^T, 3-pass bf16 split --------
// PERB: B indexed per image (m0>>14).
template <int N, bool PERB>
__global__ __launch_bounds__(256, 3) void gemm_mfma(const unsigned short* __restrict__ Ah,
                                                    const unsigned short* __restrict__ Al,
                                                    const unsigned short* __restrict__ Bh,
                                                    const unsigned short* __restrict__ Bl,
                                                    float* __restrict__ Co) {
  __shared__ __align__(16) unsigned short sAh[2][128 * 32];
  __shared__ __align__(16) unsigned short sAl[2][128 * 32];
  __shared__ __align__(16) unsigned short sBh[2][64 * 32];
  __shared__ __align__(16) unsigned short sBl[2][64 * 32];
  const int t = threadIdx.x;
  const int lane = t & 63;
  const int wid = t >> 6;
  const int m0 = blockIdx.x * 128;
  const int n0 = blockIdx.y * 64;
  const size_t boff = PERB ? (size_t)(m0 >> 14) * (192 * 192) : 0;
  const int wr = wid >> 1, wc = wid & 1;
  const int fr_row = lane & 15;
  const int fr_swz = ((lane >> 4) ^ (lane & 3)) << 3;

  f32x4 acc[4][2] = {};
  bf16x8 rg[6];

  auto stage_load = [&](int k0) {
#pragma unroll
    for (int r = 0; r < 2; ++r) {
      const int idx = t + (r << 8);
      const int row = idx >> 2, sl = idx & 3;
      const size_t go = (size_t)(m0 + row) * K + k0 + (sl << 3);
      rg[r]     = *(const bf16x8*)&Ah[go];
      rg[2 + r] = *(const bf16x8*)&Al[go];
    }
    {
      const int row = t >> 2, sl = t & 3;
      const size_t go = boff + (size_t)(n0 + row) * K + k0 + (sl << 3);
      rg[4] = *(const bf16x8*)&Bh[go];
      rg[5] = *(const bf16x8*)&Bl[go];
    }
  };
  auto stage_write = [&](int buf) {
#pragma unroll
    for (int r = 0; r < 2; ++r) {
      const int idx = t + (r << 8);
      const int row = idx >> 2, sl = idx & 3;
      const int ph = row * 32 + ((sl ^ (row & 3)) << 3);
      *(bf16x8*)&sAh[buf][ph] = rg[r];
      *(bf16x8*)&sAl[buf][ph] = rg[2 + r];
    }
    {
      const int row = t >> 2, sl = t & 3;
      const int ph = row * 32 + ((sl ^ (row & 3)) << 3);
      *(bf16x8*)&sBh[buf][ph] = rg[4];
      *(bf16x8*)&sBl[buf][ph] = rg[5];
    }
  };

  stage_load(0);
  stage_write(0);
  __syncthreads();
#pragma unroll
  for (int ks = 0; ks < 6; ++ks) {
    if (ks < 5) stage_load((ks + 1) * 32);
    {
      const int buf = ks & 1;
      bf16x8 fah[4], fal[4], fbh[2], fbl[2];
#pragma unroll
      for (int i = 0; i < 4; ++i) {
        const int row = wr * 64 + i * 16 + fr_row;
        fah[i] = *(const bf16x8*)&sAh[buf][row * 32 + fr_swz];
        fal[i] = *(const bf16x8*)&sAl[buf][row * 32 + fr_swz];
      }
#pragma unroll
      for (int j = 0; j < 2; ++j) {
        const int row = wc * 32 + j * 16 + fr_row;
        fbh[j] = *(const bf16x8*)&sBh[buf][row * 32 + fr_swz];
        fbl[j] = *(const bf16x8*)&sBl[buf][row * 32 + fr_swz];
      }
#pragma unroll
      for (int i = 0; i < 4; ++i)
#pragma unroll
        for (int j = 0; j < 2; ++j) {
          acc[i][j] = __builtin_amdgcn_mfma_f32_16x16x32_bf16(fah[i], fbh[j], acc[i][j], 0, 0, 0);
          acc[i][j] = __builtin_amdgcn_mfma_f32_16x16x32_bf16(fah[i], fbl[j], acc[i][j], 0, 0, 0);
          acc[i][j] = __builtin_amdgcn_mfma_f32_16x16x32_bf16(fal[i], fbh[j], acc[i][j], 0, 0, 0);
        }
    }
    if (ks < 5) {
      __syncthreads();
      stage_write((ks + 1) & 1);
      __syncthreads();
    }
  }

  const int er = (lane >> 4) << 2;  // C/D: col=lane&15, row=(lane>>4)*4+reg
  const int ec = lane & 15;
#pragma unroll
  for (int i = 0; i < 4; ++i)
#pragma unroll
    for (int j = 0; j < 2; ++j) {
      float* cp = &Co[(size_t)(m0 + wr * 64 + i * 16 + er) * N + n0 + wc * 32 + j * 16 + ec];
#pragma unroll
      for (int r = 0; r < 4; ++r) cp[(size_t)r * N] = acc[i][j][r];
    }
}

// ---- depthwise 3x3 SAME; q,k -> fp32 [p][384], v -> bf16 hi/lo [p][192] ----
__global__ __launch_bounds__(256) void dwconv3x3(const float* __restrict__ in,
                                                 const float* __restrict__ wdw,
                                                 float* __restrict__ dwq,
                                                 unsigned short* __restrict__ vh,
                                                 unsigned short* __restrict__ vl) {
  const int t = blockIdx.x * 256 + threadIdx.x;  // float4 index over npix*144
  const int c4 = t % 144;
  const int p = t / 144;
  const int pi = p & 16383;
  const int imgbase = p - pi;
  const int y = pi >> 7;
  const int x = pi & 127;
  float4 acc = make_float4(0.f, 0.f, 0.f, 0.f);
#pragma unroll
  for (int dy = -1; dy <= 1; ++dy) {
    const int yy = y + dy;
    if ((unsigned)yy >= 128u) continue;
#pragma unroll
    for (int dx = -1; dx <= 1; ++dx) {
      const int xx = x + dx;
      if ((unsigned)xx >= 128u) continue;
      const float4 v = *(const float4*)&in[(size_t)(imgbase + (yy << 7) + xx) * C3 + c4 * 4];
      const float4 w = *(const float4*)&wdw[(size_t)((dy + 1) * 3 + (dx + 1)) * C3 + c4 * 4];
      acc.x += v.x * w.x;
      acc.y += v.y * w.y;
      acc.z += v.z * w.z;
      acc.w += v.w * w.w;
    }
  }
  if (c4 < 96) {
    *(float4*)&dwq[(size_t)p * 384 + c4 * 4] = acc;
  } else {
    const int cc = (c4 - 96) * 4;
    const float vv[4] = {acc.x, acc.y, acc.z, acc.w};
    ushort4 h4, l4;
    unsigned short* hp = (unsigned short*)&h4;
    unsigned short* lp = (unsigned short*)&l4;
#pragma unroll
    for (int j = 0; j < 4; ++j) {
      const unsigned short h = f2bf(vv[j]);
      hp[j] = h;
      lp[j] = f2bf(vv[j] - bf2f(h));
    }
    *(ushort4*)&vh[(size_t)p * 192 + cc] = h4;
    *(ushort4*)&vl[(size_t)p * 192 + cc] = l4;
  }
}

// ------- Gram: G[img][h][c][d] += sum_s q[s,c]*k[s,d]; + row sum-of-squares -
__global__ __launch_bounds__(256) void gram48(const float* __restrict__ dwq,
                                              float* __restrict__ G,
                                              float* __restrict__ ssqq,
                                              float* __restrict__ ssqk) {
  __shared__ float qs[64][48];
  __shared__ float ks[64][48];
  const int tid = threadIdx.x;
  const int h = blockIdx.y;
  const int img = blockIdx.z;
  const int s0 = (img << 14) + blockIdx.x * 256;
  const int qoff = h * CH;
  const int koff = 192 + h * CH;
  const int c3 = (tid >> 4) * 3;
  const int d3 = (tid & 15) * 3;
  float acc[3][3] = {};
  float sq = 0.f, sk = 0.f;
  for (int sub = 0; sub < 4; ++sub) {
    const int sbase = s0 + sub * 64;
#pragma unroll
    for (int r = 0; r < 3; ++r) {
      const int idx = tid + r * 256;
      const int row = idx / 12;
      const int cc4 = idx % 12;
      const float* src = &dwq[(size_t)(sbase + row) * 384];
      *(float4*)&qs[row][cc4 * 4] = *(const float4*)&src[qoff + cc4 * 4];
      *(float4*)&ks[row][cc4 * 4] = *(const float4*)&src[koff + cc4 * 4];
    }
    __syncthreads();
#pragma unroll 4
    for (int s = 0; s < 64; ++s) {
      const float qv[3] = {qs[s][c3], qs[s][c3 + 1], qs[s][c3 + 2]};
      const float kv[3] = {ks[s][d3], ks[s][d3 + 1], ks[s][d3 + 2]};
#pragma unroll
      for (int i = 0; i < 3; ++i)
#pragma unroll
        for (int j = 0; j < 3; ++j) acc[i][j] += qv[i] * kv[j];
    }
    if (tid < 48) {
#pragma unroll 4
      for (int s = 0; s < 64; ++s) { const float v = qs[s][tid]; sq += v * v; }
    } else if (tid >= 64 && tid < 112) {
      const int cc = tid - 64;
#pragma unroll 4
      for (int s = 0; s < 64; ++s) { const float v = ks[s][cc]; sk += v * v; }
    }
    __syncthreads();
  }
  float* Gm = &G[(size_t)(img * 4 + h) * 2304];
#pragma unroll
  for (int i = 0; i < 3; ++i)
#pragma unroll
    for (int j = 0; j < 3; ++j) atomicAdd(&Gm[(c3 + i) * 48 + d3 + j], acc[i][j]);
  if (tid < 48) atomicAdd(&ssqq[img * 192 + h * CH + tid], sq);
  else if (tid >= 64 && tid < 112) atomicAdd(&ssqk[img * 192 + h * CH + tid - 64], sk);
}

// ---- softmax over d of G*temp/(|q||k|), one wave per (img,h,row) -----------
__global__ __launch_bounds__(64) void attn_softmax(const float* __restrict__ G,
                                                   const float* __restrict__ ssqq,
                                                   const float* __restrict__ ssqk,
                                                   const float* __restrict__ temp,
                                                   float* __restrict__ attn) {
  const int r = blockIdx.x;          // 0..47
  const int h = blockIdx.y & 3;
  const int img = blockIdx.y >> 2;
  const int lane = threadIdx.x;
  const size_t base = (size_t)(img * 4 + h) * 2304;
  const float t = temp[h];
  const float qn = ssqq[img * 192 + h * CH + r];
  float val = -1e30f;
  if (lane < 48) {
    const float kn = ssqk[img * 192 + h * CH + lane];
    val = G[base + r * 48 + lane] * t * rsqrtf(qn * kn);
  }
  float m = val;
#pragma unroll
  for (int off = 32; off; off >>= 1) m = fmaxf(m, __shfl_xor(m, off));
  const float e = (lane < 48) ? expf(val - m) : 0.f;
  float ssum = e;
#pragma unroll
  for (int off = 32; off; off >>= 1) ssum += __shfl_xor(ssum, off);
  if (lane < 48) attn[base + r * 48 + lane] = e / ssum;
}

// ---- W_eff^T[img][n][D] = sum_c' A[img][h(D)][c'][D%48] * Wp[48h+c'][n] ----
__global__ __launch_bounds__(256) void make_weff(const float* __restrict__ attn,
                                                 const float* __restrict__ wproj,
                                                 unsigned short* __restrict__ weh,
                                                 unsigned short* __restrict__ wel) {
  const int t = blockIdx.x * 256 + threadIdx.x;   // over NI*192*192
  const int img = t / 36864;
  const int r = t % 36864;
  const int n = r / 192;
  const int D = r % 192;
  const int h = D / 48, dd = D % 48;
  const float* A = &attn[(size_t)(img * 4 + h) * 2304 + dd];
  const float* W = &wproj[(size_t)(h * 48) * 192 + n];
  float acc = 0.f;
#pragma unroll
  for (int c = 0; c < 48; ++c) acc += A[c * 48] * W[c * 192];
  const unsigned short hb = f2bf(acc);
  weh[(size_t)img * 36864 + n * 192 + D] = hb;
  wel[(size_t)img * 36864 + n * 192 + D] = f2bf(acc - bf2f(hb));
}

}  // namespace

extern "C" void kernel_launch(void* const* d_in, const int* in_sizes, int n_in,
                              void* d_out, int out_size, void* d_ws, size_t ws_size,
                              hipStream_t stream) {
  const float* x      = (const float*)d_in[0];
  const float* w_qkv  = (const float*)d_in[1];
  const float* w_dw   = (const float*)d_in[2];
  const float* w_proj = (const float*)d_in[3];
  const float* temp   = (const float*)d_in[4];
  float* out = (float*)d_out;

  // NI images per pass. Layout bytes: NI=2 ≈ 202 MB (ws is 256 MiB), NI=1 ≈ 127 MB.
  auto layout_bytes = [](int NI) -> size_t {
    return (size_t)NI * HW * 576 * 4       // qkv fp32
         + (size_t)NI * HW * 384 * 4       // dwq fp32 (q,k)
         + (size_t)NI * HW * 192 * 2 * 2   // vh, vl
         + (size_t)4 * HW * 192 * 2 * 2    // xh, xl (all 4 images)
         + 2 * 221184                      // wqh, wql
         + (size_t)NI * 38400              // G, ssqq, ssqk
         + (size_t)NI * 147456             // attnb
         + (size_t)NI * 147456;            // weh, wel
  };
  const int NI = (ws_size >= layout_bytes(2)) ? 2 : 1;
  const int npass = 4 / NI;
  const int npix = NI * HW;

  char* p = (char*)d_ws;
  float* qkv = (float*)p;            p += (size_t)npix * 576 * 4;
  float* dwq = (float*)p;            p += (size_t)npix * 384 * 4;
  unsigned short* vh = (unsigned short*)p;  p += (size_t)npix * 192 * 2;
  unsigned short* vl = (unsigned short*)p;  p += (size_t)npix * 192 * 2;
  unsigned short* xh = (unsigned short*)p;  p += (size_t)4 * HW * 192 * 2;
  unsigned short* xl = (unsigned short*)p;  p += (size_t)4 * HW * 192 * 2;
  unsigned short* wqh = (unsigned short*)p; p += 221184;
  unsigned short* wql = (unsigned short*)p; p += 221184;
  float* G    = (float*)p;           p += (size_t)NI * 36864;
  float* ssqq = (float*)p;           p += (size_t)NI * 768;
  float* ssqk = (float*)p;           p += (size_t)NI * 768;
  float* attnb = (float*)p;          p += (size_t)NI * 147456;
  unsigned short* weh = (unsigned short*)p; p += (size_t)NI * 73728;
  unsigned short* wel = (unsigned short*)p;

  cvt_wqkv<<<432, 256, 0, stream>>>(w_qkv, wqh, wql);
  cvt_split<<<4 * HW * 192 / 1024, 256, 0, stream>>>(x, xh, xl);

  for (int pass = 0; pass < npass; ++pass) {
    const size_t arow = (size_t)pass * npix * 192;
    float* outb = out + (size_t)pass * npix * C;
    hipMemsetAsync(G, 0, (size_t)NI * 38400, stream);  // G+ssqq+ssqk contiguous
    gemm_mfma<576, false><<<dim3(npix / 128, 9), 256, 0, stream>>>(
        xh + arow, xl + arow, wqh, wql, qkv);
    dwconv3x3<<<npix * 144 / 256, 256, 0, stream>>>(qkv, w_dw, dwq, vh, vl);
    gram48<<<dim3(64, 4, NI), 256, 0, stream>>>(dwq, G, ssqq, ssqk);
    attn_softmax<<<dim3(48, 4 * NI), 64, 0, stream>>>(G, ssqq, ssqk, temp, attnb);
    make_weff<<<NI * 144, 256, 0, stream>>>(attnb, w_proj, weh, wel);
    gemm_mfma<192, true><<<dim3(npix / 128, 3), 256, 0, stream>>>(
        vh, vl, weh, wel, outb);
  }
}